// Round 10
// baseline (43.996 us; speedup 1.0000x reference)
//
#include <hip/hip_runtime.h>
#include <hip/hip_fp16.h>

#define U 128
#define NSEG 32
#define NPATH 512
#define ROW (NSEG * U)   // 4096 elements per batch row
#define NW 8             // waves per tp block (512 threads)
#define MPAD 128         // meta pad so wave preloads never run off the end

// Path metadata, grouped (order-preserving) by pout.
// pp = p0 | (p1 << 16); c2 = bits of half2{c, c}
struct Meta { unsigned pp; unsigned c2; };
struct WS {
    Meta meta[NPATH + MPAD]; // padded; pad entries are zero
    int  segstart[NSEG + 1]; // CSR boundaries into meta[]
    int  wsplit[NW + 1];     // segment-boundary split per wave
};

template <typename T, typename F> __device__ inline T bcast(F v) {
    union { F f; T t; } u; u.f = v; return u.t;
}

// meta[rel] from the wave's register-resident slice (m0: rel 0..63, m1: 64..127)
__device__ inline uint2 get_meta(uint2 m0, uint2 m1, int rel) {
    const uint2 src = (rel < 64) ? m0 : m1;   // wave-uniform select
    const int   l   = rel & 63;
    uint2 r;
    r.x = (unsigned)__builtin_amdgcn_readlane((int)src.x, l);
    r.y = (unsigned)__builtin_amdgcn_readlane((int)src.y, l);
    return r;
}

// One block, 512 threads: thread k owns path k. Deterministic parallel
// counting-sort by pout (original-k order preserved within each segment).
__global__ __launch_bounds__(512) void build_csr(const float* __restrict__ coeffs,
                                                 const int* __restrict__ p0,
                                                 const int* __restrict__ p1,
                                                 const int* __restrict__ pout,
                                                 WS* __restrict__ ws) {
    __shared__ int wcnt[NPATH / 64][NSEG];   // per-wave per-segment counts
    __shared__ int wpre[NPATH / 64][NSEG];   // prefix over earlier waves
    __shared__ int sseg[NSEG + 1];
    __shared__ int stot[NSEG];

    const int k    = threadIdx.x;
    const int lane = k & 63;
    const int wave = k >> 6;

    const int   po = pout[k];
    const int   a0 = p0[k];
    const int   a1 = p1[k];
    const float c  = coeffs[k];

    // zero the pad
    if (k < MPAD) { Meta z; z.pp = 0u; z.c2 = 0u; ws->meta[NPATH + k] = z; }

    // rank within wave + per-wave counts, via 32 ballots
    const unsigned long long lt = (1ull << lane) - 1ull;
    int rank = 0;
    #pragma unroll
    for (int s = 0; s < NSEG; ++s) {
        unsigned long long m = __ballot(po == s);
        if (po == s)  rank = (int)__popcll(m & lt);
        if (lane == s) wcnt[wave][s] = (int)__popcll(m);
    }
    __syncthreads();

    // per-segment: prefix over waves + totals (threads 0..31)
    if (k < NSEG) {
        int tot = 0;
        #pragma unroll
        for (int w = 0; w < NPATH / 64; ++w) { wpre[w][k] = tot; tot += wcnt[w][k]; }
        stot[k] = tot;
    }
    __syncthreads();

    // exclusive scan of totals over segments (wave 0)
    if (k < 64) {
        int v = (k < NSEG) ? stot[k] : 0;
        int inc = v;
        #pragma unroll
        for (int d = 1; d < 64; d <<= 1) {
            int t = __shfl_up(inc, d, 64);
            if (k >= d) inc += t;
        }
        int excl = inc - v;
        if (k < NSEG) sseg[k] = excl;
        if (k == NSEG - 1) sseg[NSEG] = excl + v;
    }
    __syncthreads();

    // scatter (deterministic position)
    {
        const __half   h  = __float2half_rn(c);
        const __half2  h2 = __halves2half2(h, h);
        Meta m;
        m.pp = (unsigned)a0 | ((unsigned)a1 << 16);
        m.c2 = bcast<unsigned>(h2);
        ws->meta[sseg[po] + wpre[wave][po] + rank] = m;
    }
    if (k <= NSEG) ws->segstart[k] = sseg[k];

    // balanced NW-way split boundaries (wave 0); argmin |segstart - target|
    if (k < 64) {
        #pragma unroll
        for (int w = 1; w < NW; ++w) {
            const int target = (NPATH * w) / NW;
            int key;
            if (k <= NSEG) {
                int d = sseg[k] - target; if (d < 0) d = -d;
                key = (d << 6) | k;
            } else key = 0x7fffffff;
            #pragma unroll
            for (int m = 32; m >= 1; m >>= 1) {
                int o = __shfl_xor(key, m, 64);
                key = (o < key) ? o : key;
            }
            if (k == 0) ws->wsplit[w] = key & 63;
        }
        if (k == 0) { ws->wsplit[0] = 0; ws->wsplit[NW] = NSEG; }
    }
}

// One block (512 threads, 8 waves) per batch row. Rows staged in LDS as F16
// (16 KiB). Metadata lives in each wave's REGISTERS (preloaded slice) and is
// consumed via v_readlane (no lgkmcnt) — the per-group dependent chain has a
// single LDS round-trip: readlane -> addr -> ds_read_b64 -> pk_fma.
// Pair scheme: lanes 0-31 path j, lanes 32-63 path j+1, 4 elems per lane.
__global__ __launch_bounds__(512) void tp_kernel(const float* __restrict__ x0,
                                                 const float* __restrict__ x1,
                                                 const WS* __restrict__ ws,
                                                 float* __restrict__ out) {
    __shared__ __align__(16) __half xh[2 * ROW];   // x0 at [0,ROW), x1 at [ROW,2*ROW)
    __shared__ int sseg[NSEG + 1];
    __shared__ int ssplit[NW + 1];

    const int b   = blockIdx.x;
    const int tid = threadIdx.x;

    // stage + convert rows (coalesced float4 in, uint2 (4×f16) to LDS)
    {
        const float4* g0 = reinterpret_cast<const float4*>(x0 + (size_t)b * ROW);
        const float4* g1 = reinterpret_cast<const float4*>(x1 + (size_t)b * ROW);
        #pragma unroll
        for (int j = 0; j < (ROW / 4) / 512; ++j) {   // 2 iters each
            const int e = tid + j * 512;              // float4 index
            const float4 v0 = g0[e];
            const float4 v1 = g1[e];
            uint2 h0, h1;
            h0.x = bcast<unsigned>(__float22half2_rn(make_float2(v0.x, v0.y)));
            h0.y = bcast<unsigned>(__float22half2_rn(make_float2(v0.z, v0.w)));
            h1.x = bcast<unsigned>(__float22half2_rn(make_float2(v1.x, v1.y)));
            h1.y = bcast<unsigned>(__float22half2_rn(make_float2(v1.z, v1.w)));
            *reinterpret_cast<uint2*>(&xh[e * 4])       = h0;
            *reinterpret_cast<uint2*>(&xh[ROW + e * 4]) = h1;
        }
    }
    if (tid < NSEG + 1) sseg[tid] = ws->segstart[tid];
    if (tid < NW + 1)   ssplit[tid] = ws->wsplit[tid];
    __syncthreads();

    const int wave = tid >> 6;
    const int lane = tid & 63;
    const int half = lane >> 5;   // 0: low 32 lanes (path j), 1: high (path j+1)
    const int sub  = lane & 31;   // 4-element slot within a segment

    const int sBeg = __builtin_amdgcn_readfirstlane(ssplit[wave]);
    const int sEnd = __builtin_amdgcn_readfirstlane(ssplit[wave + 1]);
    const int jw   = __builtin_amdgcn_readfirstlane(sseg[sBeg]);

    // preload this wave's meta slice (covers its whole path range; <=128 paths)
    const uint2* gmeta = reinterpret_cast<const uint2*>(ws->meta);
    const uint2 mr0 = gmeta[jw + lane];
    const uint2 mr1 = gmeta[jw + 64 + lane];

    float* outrow = out + (size_t)b * ROW;
    const __half2 zero2 = __halves2half2(__float2half_rn(0.f), __float2half_rn(0.f));

    for (int s = sBeg; s < sEnd; ++s) {
        const int jb = __builtin_amdgcn_readfirstlane(sseg[s]);
        const int je = __builtin_amdgcn_readfirstlane(sseg[s + 1]);
        __half2 aA0 = zero2, aA1 = zero2;   // group A accum (4 elems)
        __half2 aB0 = zero2, aB1 = zero2;   // group B (unrolled)
        int j = jb;
        for (; j + 3 < je; j += 4) {   // 4 paths in flight
            const uint2 mA0 = get_meta(mr0, mr1, j - jw);
            const uint2 mA1 = get_meta(mr0, mr1, j + 1 - jw);
            const uint2 mB0 = get_meta(mr0, mr1, j + 2 - jw);
            const uint2 mB1 = get_meta(mr0, mr1, j + 3 - jw);
            const unsigned ppA = half ? mA1.x : mA0.x;
            const unsigned cAu = half ? mA1.y : mA0.y;
            const unsigned ppB = half ? mB1.x : mB0.x;
            const unsigned cBu = half ? mB1.y : mB0.y;
            const int oA0 = (int)(ppA & 0xffffu) << 7;
            const int oA1 = (int)(ppA >> 16)     << 7;
            const int oB0 = (int)(ppB & 0xffffu) << 7;
            const int oB1 = (int)(ppB >> 16)     << 7;
            const uint2 uA = *reinterpret_cast<const uint2*>(&xh[oA0 + sub * 4]);
            const uint2 wA = *reinterpret_cast<const uint2*>(&xh[ROW + oA1 + sub * 4]);
            const uint2 uB = *reinterpret_cast<const uint2*>(&xh[oB0 + sub * 4]);
            const uint2 wB = *reinterpret_cast<const uint2*>(&xh[ROW + oB1 + sub * 4]);
            const __half2 cA = bcast<__half2>(cAu);
            const __half2 cB = bcast<__half2>(cBu);
            aA0 = __hfma2(__hmul2(bcast<__half2>(uA.x), bcast<__half2>(wA.x)), cA, aA0);
            aA1 = __hfma2(__hmul2(bcast<__half2>(uA.y), bcast<__half2>(wA.y)), cA, aA1);
            aB0 = __hfma2(__hmul2(bcast<__half2>(uB.x), bcast<__half2>(wB.x)), cB, aB0);
            aB1 = __hfma2(__hmul2(bcast<__half2>(uB.y), bcast<__half2>(wB.y)), cB, aB1);
        }
        for (; j + 1 < je; j += 2) {   // 2-path tail
            const uint2 m0 = get_meta(mr0, mr1, j - jw);
            const uint2 m1 = get_meta(mr0, mr1, j + 1 - jw);
            const unsigned pp = half ? m1.x : m0.x;
            const unsigned cu = half ? m1.y : m0.y;
            const int o0 = (int)(pp & 0xffffu) << 7;
            const int o1 = (int)(pp >> 16)     << 7;
            const uint2 u = *reinterpret_cast<const uint2*>(&xh[o0 + sub * 4]);
            const uint2 w = *reinterpret_cast<const uint2*>(&xh[ROW + o1 + sub * 4]);
            const __half2 c = bcast<__half2>(cu);
            aA0 = __hfma2(__hmul2(bcast<__half2>(u.x), bcast<__half2>(w.x)), c, aA0);
            aA1 = __hfma2(__hmul2(bcast<__half2>(u.y), bcast<__half2>(w.y)), c, aA1);
        }
        if (j < je) {                  // odd tail: upper half contributes 0
            const uint2 m0 = get_meta(mr0, mr1, j - jw);
            const int o0 = (int)(m0.x & 0xffffu) << 7;
            const int o1 = (int)(m0.x >> 16)     << 7;
            const uint2 u = *reinterpret_cast<const uint2*>(&xh[o0 + sub * 4]);
            const uint2 w = *reinterpret_cast<const uint2*>(&xh[ROW + o1 + sub * 4]);
            const __half2 c = (half == 0) ? bcast<__half2>(m0.y) : zero2;
            aA0 = __hfma2(__hmul2(bcast<__half2>(u.x), bcast<__half2>(w.x)), c, aA0);
            aA1 = __hfma2(__hmul2(bcast<__half2>(u.y), bcast<__half2>(w.y)), c, aA1);
        }
        // combine unroll groups + convert to f32
        const float2 f0a = __half22float2(aA0), f0b = __half22float2(aB0);
        const float2 f1a = __half22float2(aA1), f1b = __half22float2(aB1);
        float4 a;
        a.x = f0a.x + f0b.x;
        a.y = f0a.y + f0b.y;
        a.z = f1a.x + f1b.x;
        a.w = f1a.y + f1b.y;
        // cross-half reduce (path j + path j+1)
        a.x += __shfl_xor(a.x, 32, 64);
        a.y += __shfl_xor(a.y, 32, 64);
        a.z += __shfl_xor(a.z, 32, 64);
        a.w += __shfl_xor(a.w, 32, 64);
        if (half == 0)
            reinterpret_cast<float4*>(outrow + s * U)[sub] = a;
    }
}

extern "C" void kernel_launch(void* const* d_in, const int* in_sizes, int n_in,
                              void* d_out, int out_size, void* d_ws, size_t ws_size,
                              hipStream_t stream) {
    const float* x0     = (const float*)d_in[0];
    const float* x1     = (const float*)d_in[1];
    const float* coeffs = (const float*)d_in[2];
    const int*   p0     = (const int*)d_in[3];
    const int*   p1     = (const int*)d_in[4];
    const int*   pout   = (const int*)d_in[5];
    float* out = (float*)d_out;
    WS* ws = (WS*)d_ws;

    build_csr<<<1, 512, 0, stream>>>(coeffs, p0, p1, pout, ws);
    tp_kernel<<<2048, 512, 0, stream>>>(x0, x1, ws, out);
}

// Round 11
// 43.748 us; speedup vs baseline: 1.0057x; 1.0057x over previous
//
#include <hip/hip_runtime.h>
#include <hip/hip_fp16.h>

#define U 128
#define NSEG 32
#define NPATH 512
#define ROW (NSEG * U)     // 4096 elements per batch row
#define NW 8               // waves per tp block (512 threads)
#define NMETA 640          // padded meta capacity (max 512 + 32*3 = 608)
#define SEGB 272           // LDS bytes per segment per operand (256 + 16 stagger)
#define XH1 (NSEG * SEGB)  // x1 base offset within a row buffer
#define ROWBUF (2 * NSEG * SEGB)   // bytes per row buffer (x0h + x1h) = 17408
#define ROWS_PER_BLOCK 2
#define NBLK 1024

// Path metadata, grouped (order-preserving) by pout, each segment's list
// zero-padded to a multiple of 4. pp = p0 | (p1 << 16); c2 = half2{c, c} bits.
struct Meta { unsigned pp; unsigned c2; };
struct WS {
    Meta meta[NMETA];
    int  segstart[NSEG + 1]; // PADDED CSR boundaries (all multiples of 4)
    int  wsplit[NW + 1];     // segment-boundary split per wave
};

template <typename T, typename F> __device__ inline T bcast(F v) {
    union { F f; T t; } u; u.f = v; return u.t;
}

// One block, 512 threads: thread k owns path k. Deterministic parallel
// counting-sort by pout; per-segment lists zero-padded to x4.
__global__ __launch_bounds__(512) void build_csr(const float* __restrict__ coeffs,
                                                 const int* __restrict__ p0,
                                                 const int* __restrict__ p1,
                                                 const int* __restrict__ pout,
                                                 WS* __restrict__ ws) {
    __shared__ int wcnt[NPATH / 64][NSEG];
    __shared__ int wpre[NPATH / 64][NSEG];
    __shared__ int sseg[NSEG + 1];
    __shared__ int stot[NSEG];

    const int k    = threadIdx.x;
    const int lane = k & 63;
    const int wave = k >> 6;

    const int   po = pout[k];
    const int   a0 = p0[k];
    const int   a1 = p1[k];
    const float c  = coeffs[k];

    // zero ALL meta slots (pads must be {pp=0, c2=0})
    for (int i = k; i < NMETA; i += 512) { Meta z; z.pp = 0u; z.c2 = 0u; ws->meta[i] = z; }

    // rank within wave + per-wave counts, via 32 ballots
    const unsigned long long lt = (1ull << lane) - 1ull;
    int rank = 0;
    #pragma unroll
    for (int s = 0; s < NSEG; ++s) {
        unsigned long long m = __ballot(po == s);
        if (po == s)  rank = (int)__popcll(m & lt);
        if (lane == s) wcnt[wave][s] = (int)__popcll(m);
    }
    __syncthreads();

    // per-segment: prefix over waves + totals (threads 0..31)
    if (k < NSEG) {
        int tot = 0;
        #pragma unroll
        for (int w = 0; w < NPATH / 64; ++w) { wpre[w][k] = tot; tot += wcnt[w][k]; }
        stot[k] = tot;
    }
    __syncthreads();

    // exclusive scan of PADDED totals over segments (wave 0)
    if (k < 64) {
        int v = (k < NSEG) ? ((stot[k] + 3) & ~3) : 0;   // pad to x4
        int inc = v;
        #pragma unroll
        for (int d = 1; d < 64; d <<= 1) {
            int t = __shfl_up(inc, d, 64);
            if (k >= d) inc += t;
        }
        int excl = inc - v;
        if (k < NSEG) sseg[k] = excl;
        if (k == NSEG - 1) sseg[NSEG] = excl + v;
    }
    __syncthreads();

    // scatter (deterministic position within padded segment list)
    {
        const __half   h  = __float2half_rn(c);
        const __half2  h2 = __halves2half2(h, h);
        Meta m;
        m.pp = (unsigned)a0 | ((unsigned)a1 << 16);
        m.c2 = bcast<unsigned>(h2);
        ws->meta[sseg[po] + wpre[wave][po] + rank] = m;
    }
    if (k <= NSEG) ws->segstart[k] = sseg[k];

    // balanced NW-way split boundaries on padded counts (wave 0)
    if (k < 64) {
        const int tot = sseg[NSEG];
        #pragma unroll
        for (int w = 1; w < NW; ++w) {
            const int target = (tot * w) / NW;
            int key;
            if (k <= NSEG) {
                int d = sseg[k] - target; if (d < 0) d = -d;
                key = (d << 6) | k;
            } else key = 0x7fffffff;
            #pragma unroll
            for (int m = 32; m >= 1; m >>= 1) {
                int o = __shfl_xor(key, m, 64);
                key = (o < key) ? o : key;
            }
            if (k == 0) ws->wsplit[w] = key & 63;
        }
        if (k == 0) { ws->wsplit[0] = 0; ws->wsplit[NW] = NSEG; }
    }
}

// convert one float4 (4 f32) to 8 bytes of f16
__device__ inline uint2 cvt4(float4 v) {
    uint2 r;
    r.x = bcast<unsigned>(__float22half2_rn(make_float2(v.x, v.y)));
    r.y = bcast<unsigned>(__float22half2_rn(make_float2(v.z, v.w)));
    return r;
}

// One block (512 threads, 8 waves) per 2 batch rows, register double-buffer.
// Quarter scheme: lane = 16*g + t; group g takes path j+g; lane reads 8 f16
// (ds_read_b128) at staggered segment base seg*SEGB + t*16. Padded CSR ->
// no tails. Cross-group reduce in f32 (shfl_xor 16,32); 32-lane f32 stores.
__global__ __launch_bounds__(512) void tp_kernel(const float* __restrict__ x0,
                                                 const float* __restrict__ x1,
                                                 const WS* __restrict__ ws,
                                                 float* __restrict__ out) {
    __shared__ __align__(16) char xbuf[2][ROWBUF];   // 2 x 17408 B
    __shared__ Meta smeta[NMETA];
    __shared__ int  sseg[NSEG + 1];
    __shared__ int  ssplit[NW + 1];

    const int tid = threadIdx.x;
    const int b0  = blockIdx.x * ROWS_PER_BLOCK;

    // ---- issue row0 + row1 global loads (regs), then convert/write row0 ----
    const float4* g00 = reinterpret_cast<const float4*>(x0 + (size_t)b0 * ROW);
    const float4* g01 = reinterpret_cast<const float4*>(x1 + (size_t)b0 * ROW);
    const float4* g10 = reinterpret_cast<const float4*>(x0 + (size_t)(b0 + 1) * ROW);
    const float4* g11 = reinterpret_cast<const float4*>(x1 + (size_t)(b0 + 1) * ROW);
    const float4 A0 = g00[tid], A1 = g00[tid + 512];
    const float4 A2 = g01[tid], A3 = g01[tid + 512];
    const float4 B0 = g10[tid], B1 = g10[tid + 512];
    const float4 B2 = g11[tid], B3 = g11[tid + 512];

    // stage helper: float4 index e of an operand row -> LDS byte offset
    auto wr = [&](int buf, int e, const float4& vx0, const float4& vx1) {
        const int off = (e >> 5) * SEGB + (e & 31) * 8;
        *reinterpret_cast<uint2*>(&xbuf[buf][off])       = cvt4(vx0);
        *reinterpret_cast<uint2*>(&xbuf[buf][XH1 + off]) = cvt4(vx1);
    };
    wr(0, tid, A0, A2);
    wr(0, tid + 512, A1, A3);

    // stage metadata (5 KiB) + CSR
    if (tid < NMETA / 2)
        reinterpret_cast<float4*>(smeta)[tid] =
            reinterpret_cast<const float4*>(ws->meta)[tid];
    if (tid < NSEG + 1) sseg[tid] = ws->segstart[tid];
    if (tid < NW + 1)   ssplit[tid] = ws->wsplit[tid];
    __syncthreads();

    const int wave = tid >> 6;
    const int lane = tid & 63;
    const int g    = lane >> 4;    // path group 0..3
    const int t    = lane & 15;    // 8-element u-slot

    const int sBeg = __builtin_amdgcn_readfirstlane(ssplit[wave]);
    const int sEnd = __builtin_amdgcn_readfirstlane(ssplit[wave + 1]);
    const int tOff = t << 4;       // byte offset within segment

    #pragma unroll
    for (int r = 0; r < ROWS_PER_BLOCK; ++r) {
        const char* xb = xbuf[r];
        float* outrow = out + (size_t)(b0 + r) * ROW;

        for (int s = sBeg; s < sEnd; ++s) {
            const int jb = __builtin_amdgcn_readfirstlane(sseg[s]);
            const int je = __builtin_amdgcn_readfirstlane(sseg[s + 1]);
            __half2 aA0, aA1, aA2, aA3, aB0, aB1, aB2, aB3;
            aA0 = aA1 = aA2 = aA3 = aB0 = aB1 = aB2 = aB3 =
                bcast<__half2>(0u);
            int j = jb;
            for (; j + 7 < je; j += 8) {   // 2 groups (8 paths) in flight
                const Meta mA = smeta[j + g];
                const Meta mB = smeta[j + 4 + g];
                const uint4 uA = *reinterpret_cast<const uint4*>(
                    &xb[(int)(mA.pp & 0xffffu) * SEGB + tOff]);
                const uint4 wA = *reinterpret_cast<const uint4*>(
                    &xb[XH1 + (int)(mA.pp >> 16) * SEGB + tOff]);
                const uint4 uB = *reinterpret_cast<const uint4*>(
                    &xb[(int)(mB.pp & 0xffffu) * SEGB + tOff]);
                const uint4 wB = *reinterpret_cast<const uint4*>(
                    &xb[XH1 + (int)(mB.pp >> 16) * SEGB + tOff]);
                const __half2 cA = bcast<__half2>(mA.c2);
                const __half2 cB = bcast<__half2>(mB.c2);
                aA0 = __hfma2(__hmul2(bcast<__half2>(uA.x), bcast<__half2>(wA.x)), cA, aA0);
                aA1 = __hfma2(__hmul2(bcast<__half2>(uA.y), bcast<__half2>(wA.y)), cA, aA1);
                aA2 = __hfma2(__hmul2(bcast<__half2>(uA.z), bcast<__half2>(wA.z)), cA, aA2);
                aA3 = __hfma2(__hmul2(bcast<__half2>(uA.w), bcast<__half2>(wA.w)), cA, aA3);
                aB0 = __hfma2(__hmul2(bcast<__half2>(uB.x), bcast<__half2>(wB.x)), cB, aB0);
                aB1 = __hfma2(__hmul2(bcast<__half2>(uB.y), bcast<__half2>(wB.y)), cB, aB1);
                aB2 = __hfma2(__hmul2(bcast<__half2>(uB.z), bcast<__half2>(wB.z)), cB, aB2);
                aB3 = __hfma2(__hmul2(bcast<__half2>(uB.w), bcast<__half2>(wB.w)), cB, aB3);
            }
            if (j < je) {                  // one remaining group (padded x4)
                const Meta m = smeta[j + g];
                const uint4 u = *reinterpret_cast<const uint4*>(
                    &xb[(int)(m.pp & 0xffffu) * SEGB + tOff]);
                const uint4 w = *reinterpret_cast<const uint4*>(
                    &xb[XH1 + (int)(m.pp >> 16) * SEGB + tOff]);
                const __half2 c = bcast<__half2>(m.c2);
                aA0 = __hfma2(__hmul2(bcast<__half2>(u.x), bcast<__half2>(w.x)), c, aA0);
                aA1 = __hfma2(__hmul2(bcast<__half2>(u.y), bcast<__half2>(w.y)), c, aA1);
                aA2 = __hfma2(__hmul2(bcast<__half2>(u.z), bcast<__half2>(w.z)), c, aA2);
                aA3 = __hfma2(__hmul2(bcast<__half2>(u.w), bcast<__half2>(w.w)), c, aA3);
            }
            // combine unroll groups, convert to f32, reduce across 4 groups
            const float2 r0 = __half22float2(__hadd2(aA0, aB0));
            const float2 r1 = __half22float2(__hadd2(aA1, aB1));
            const float2 r2 = __half22float2(__hadd2(aA2, aB2));
            const float2 r3 = __half22float2(__hadd2(aA3, aB3));
            float v[8] = { r0.x, r0.y, r1.x, r1.y, r2.x, r2.y, r3.x, r3.y };
            #pragma unroll
            for (int i = 0; i < 8; ++i) {
                v[i] += __shfl_xor(v[i], 16, 64);
                v[i] += __shfl_xor(v[i], 32, 64);
            }
            if (g < 2) {
                float4 o;
                o.x = v[g * 4 + 0]; o.y = v[g * 4 + 1];
                o.z = v[g * 4 + 2]; o.w = v[g * 4 + 3];
                reinterpret_cast<float4*>(outrow + s * U)[t * 2 + g] = o;
            }
        }

        // stage row1 (loads issued long ago; convert + write, then barrier)
        if (r == 0) {
            wr(1, tid, B0, B2);
            wr(1, tid + 512, B1, B3);
            __syncthreads();
        }
    }
}

extern "C" void kernel_launch(void* const* d_in, const int* in_sizes, int n_in,
                              void* d_out, int out_size, void* d_ws, size_t ws_size,
                              hipStream_t stream) {
    const float* x0     = (const float*)d_in[0];
    const float* x1     = (const float*)d_in[1];
    const float* coeffs = (const float*)d_in[2];
    const int*   p0     = (const int*)d_in[3];
    const int*   p1     = (const int*)d_in[4];
    const int*   pout   = (const int*)d_in[5];
    float* out = (float*)d_out;
    WS* ws = (WS*)d_ws;

    build_csr<<<1, 512, 0, stream>>>(coeffs, p0, p1, pout, ws);
    tp_kernel<<<NBLK, 512, 0, stream>>>(x0, x1, ws, out);
}

// Round 12
// 34.055 us; speedup vs baseline: 1.2919x; 1.2846x over previous
//
#include <hip/hip_runtime.h>
#include <hip/hip_fp16.h>

#define U 128
#define NSEG 32
#define NPATH 512
#define ROW (NSEG * U)     // 4096 elements per batch row
#define NW 8               // waves per tp block (512 threads)
#define NMETA 640          // padded meta capacity (max 512 + 32*3 = 608)

// Path metadata, grouped (order-preserving) by pout, each segment's list
// zero-padded to a multiple of 4. pp = p0 | (p1 << 16); c2 = half2{c, c} bits.
struct Meta { unsigned pp; unsigned c2; };
struct WS {
    Meta meta[NMETA];
    int  segstart[NSEG + 1]; // PADDED CSR boundaries (all multiples of 4)
    int  wsplit[NW + 1];     // segment-boundary split per wave
};

template <typename T, typename F> __device__ inline T bcast(F v) {
    union { F f; T t; } u; u.f = v; return u.t;
}

// One block, 512 threads: thread k owns path k. Deterministic parallel
// counting-sort by pout; per-segment lists zero-padded to x4.
__global__ __launch_bounds__(512) void build_csr(const float* __restrict__ coeffs,
                                                 const int* __restrict__ p0,
                                                 const int* __restrict__ p1,
                                                 const int* __restrict__ pout,
                                                 WS* __restrict__ ws) {
    __shared__ int wcnt[NPATH / 64][NSEG];
    __shared__ int wpre[NPATH / 64][NSEG];
    __shared__ int sseg[NSEG + 1];
    __shared__ int stot[NSEG];

    const int k    = threadIdx.x;
    const int lane = k & 63;
    const int wave = k >> 6;

    const int   po = pout[k];
    const int   a0 = p0[k];
    const int   a1 = p1[k];
    const float c  = coeffs[k];

    // zero ALL meta slots (pads must be {pp=0, c2=0})
    for (int i = k; i < NMETA; i += 512) { Meta z; z.pp = 0u; z.c2 = 0u; ws->meta[i] = z; }

    // rank within wave + per-wave counts, via 32 ballots
    const unsigned long long lt = (1ull << lane) - 1ull;
    int rank = 0;
    #pragma unroll
    for (int s = 0; s < NSEG; ++s) {
        unsigned long long m = __ballot(po == s);
        if (po == s)  rank = (int)__popcll(m & lt);
        if (lane == s) wcnt[wave][s] = (int)__popcll(m);
    }
    __syncthreads();

    // per-segment: prefix over waves + totals (threads 0..31)
    if (k < NSEG) {
        int tot = 0;
        #pragma unroll
        for (int w = 0; w < NPATH / 64; ++w) { wpre[w][k] = tot; tot += wcnt[w][k]; }
        stot[k] = tot;
    }
    __syncthreads();

    // exclusive scan of PADDED totals over segments (wave 0)
    if (k < 64) {
        int v = (k < NSEG) ? ((stot[k] + 3) & ~3) : 0;   // pad to x4
        int inc = v;
        #pragma unroll
        for (int d = 1; d < 64; d <<= 1) {
            int t = __shfl_up(inc, d, 64);
            if (k >= d) inc += t;
        }
        int excl = inc - v;
        if (k < NSEG) sseg[k] = excl;
        if (k == NSEG - 1) sseg[NSEG] = excl + v;
    }
    __syncthreads();

    // scatter (deterministic position within padded segment list)
    {
        const __half   h  = __float2half_rn(c);
        const __half2  h2 = __halves2half2(h, h);
        Meta m;
        m.pp = (unsigned)a0 | ((unsigned)a1 << 16);
        m.c2 = bcast<unsigned>(h2);
        ws->meta[sseg[po] + wpre[wave][po] + rank] = m;
    }
    if (k <= NSEG) ws->segstart[k] = sseg[k];

    // balanced NW-way split boundaries on padded counts (wave 0)
    if (k < 64) {
        const int tot = sseg[NSEG];
        #pragma unroll
        for (int w = 1; w < NW; ++w) {
            const int target = (tot * w) / NW;
            int key;
            if (k <= NSEG) {
                int d = sseg[k] - target; if (d < 0) d = -d;
                key = (d << 6) | k;
            } else key = 0x7fffffff;
            #pragma unroll
            for (int m = 32; m >= 1; m >>= 1) {
                int o = __shfl_xor(key, m, 64);
                key = (o < key) ? o : key;
            }
            if (k == 0) ws->wsplit[w] = key & 63;
        }
        if (k == 0) { ws->wsplit[0] = 0; ws->wsplit[NW] = NSEG; }
    }
}

// One block (512 threads, 8 waves) per batch row. Rows in LDS as f16, PLAIN
// layout (seg s at halves [s*128, s*128+128); x1 at +ROW). Quarter scheme:
// lane = 16*g + t; group g takes path j+g; lane reads 8 f16 (ds_read_b128)
// at seg*256B + t*16B — each group's 256-B span covers all 32 banks evenly,
// conflict-free. Padded-x4 CSR -> no tails. Packed-f16 cross-group reduce.
__global__ __launch_bounds__(512) void tp_kernel(const float* __restrict__ x0,
                                                 const float* __restrict__ x1,
                                                 const WS* __restrict__ ws,
                                                 float* __restrict__ out) {
    __shared__ __align__(16) __half xh[2 * ROW];   // x0 at [0,ROW), x1 at [ROW,2*ROW)
    __shared__ Meta smeta[NMETA];
    __shared__ int  sseg[NSEG + 1];
    __shared__ int  ssplit[NW + 1];

    const int b   = blockIdx.x;
    const int tid = threadIdx.x;

    // stage + convert rows (coalesced float4 in, uint2 (4xf16) to LDS)
    {
        const float4* g0 = reinterpret_cast<const float4*>(x0 + (size_t)b * ROW);
        const float4* g1 = reinterpret_cast<const float4*>(x1 + (size_t)b * ROW);
        #pragma unroll
        for (int j = 0; j < (ROW / 4) / 512; ++j) {   // 2 iters each
            const int e = tid + j * 512;              // float4 index
            const float4 v0 = g0[e];
            const float4 v1 = g1[e];
            uint2 h0, h1;
            h0.x = bcast<unsigned>(__float22half2_rn(make_float2(v0.x, v0.y)));
            h0.y = bcast<unsigned>(__float22half2_rn(make_float2(v0.z, v0.w)));
            h1.x = bcast<unsigned>(__float22half2_rn(make_float2(v1.x, v1.y)));
            h1.y = bcast<unsigned>(__float22half2_rn(make_float2(v1.z, v1.w)));
            *reinterpret_cast<uint2*>(&xh[e * 4])       = h0;
            *reinterpret_cast<uint2*>(&xh[ROW + e * 4]) = h1;
        }
    }
    if (tid < NMETA / 2)   // 5 KiB of metadata as float4
        reinterpret_cast<float4*>(smeta)[tid] =
            reinterpret_cast<const float4*>(ws->meta)[tid];
    if (tid < NSEG + 1) sseg[tid] = ws->segstart[tid];
    if (tid < NW + 1)   ssplit[tid] = ws->wsplit[tid];
    __syncthreads();

    const int wave = tid >> 6;
    const int lane = tid & 63;
    const int g    = lane >> 4;    // path group 0..3
    const int t    = lane & 15;    // 8-element slot within a segment

    const int sBeg = __builtin_amdgcn_readfirstlane(ssplit[wave]);
    const int sEnd = __builtin_amdgcn_readfirstlane(ssplit[wave + 1]);
    const int tH   = t * 8;        // half-index offset within a segment

    float* outrow = out + (size_t)b * ROW;

    for (int s = sBeg; s < sEnd; ++s) {
        const int jb = __builtin_amdgcn_readfirstlane(sseg[s]);
        const int je = __builtin_amdgcn_readfirstlane(sseg[s + 1]);
        __half2 aA0, aA1, aA2, aA3, aB0, aB1, aB2, aB3;
        aA0 = aA1 = aA2 = aA3 = aB0 = aB1 = aB2 = aB3 = bcast<__half2>(0u);
        int j = jb;
        for (; j + 7 < je; j += 8) {   // 2 quads (8 paths) in flight
            const Meta mA = smeta[j + g];
            const Meta mB = smeta[j + 4 + g];
            const uint4 uA = *reinterpret_cast<const uint4*>(
                &xh[(int)(mA.pp & 0xffffu) * U + tH]);
            const uint4 wA = *reinterpret_cast<const uint4*>(
                &xh[ROW + (int)(mA.pp >> 16) * U + tH]);
            const uint4 uB = *reinterpret_cast<const uint4*>(
                &xh[(int)(mB.pp & 0xffffu) * U + tH]);
            const uint4 wB = *reinterpret_cast<const uint4*>(
                &xh[ROW + (int)(mB.pp >> 16) * U + tH]);
            const __half2 cA = bcast<__half2>(mA.c2);
            const __half2 cB = bcast<__half2>(mB.c2);
            aA0 = __hfma2(__hmul2(bcast<__half2>(uA.x), bcast<__half2>(wA.x)), cA, aA0);
            aA1 = __hfma2(__hmul2(bcast<__half2>(uA.y), bcast<__half2>(wA.y)), cA, aA1);
            aA2 = __hfma2(__hmul2(bcast<__half2>(uA.z), bcast<__half2>(wA.z)), cA, aA2);
            aA3 = __hfma2(__hmul2(bcast<__half2>(uA.w), bcast<__half2>(wA.w)), cA, aA3);
            aB0 = __hfma2(__hmul2(bcast<__half2>(uB.x), bcast<__half2>(wB.x)), cB, aB0);
            aB1 = __hfma2(__hmul2(bcast<__half2>(uB.y), bcast<__half2>(wB.y)), cB, aB1);
            aB2 = __hfma2(__hmul2(bcast<__half2>(uB.z), bcast<__half2>(wB.z)), cB, aB2);
            aB3 = __hfma2(__hmul2(bcast<__half2>(uB.w), bcast<__half2>(wB.w)), cB, aB3);
        }
        if (j < je) {                  // one remaining quad (padded x4)
            const Meta m = smeta[j + g];
            const uint4 u = *reinterpret_cast<const uint4*>(
                &xh[(int)(m.pp & 0xffffu) * U + tH]);
            const uint4 w = *reinterpret_cast<const uint4*>(
                &xh[ROW + (int)(m.pp >> 16) * U + tH]);
            const __half2 c = bcast<__half2>(m.c2);
            aA0 = __hfma2(__hmul2(bcast<__half2>(u.x), bcast<__half2>(w.x)), c, aA0);
            aA1 = __hfma2(__hmul2(bcast<__half2>(u.y), bcast<__half2>(w.y)), c, aA1);
            aA2 = __hfma2(__hmul2(bcast<__half2>(u.z), bcast<__half2>(w.z)), c, aA2);
            aA3 = __hfma2(__hmul2(bcast<__half2>(u.w), bcast<__half2>(w.w)), c, aA3);
        }
        // combine unroll quads (packed f16), reduce across 4 groups (packed)
        __half2 v0 = __hadd2(aA0, aB0);
        __half2 v1 = __hadd2(aA1, aB1);
        __half2 v2 = __hadd2(aA2, aB2);
        __half2 v3 = __hadd2(aA3, aB3);
        #define RED(v)                                                        \
            v = __hadd2(v, bcast<__half2>((unsigned)__shfl_xor(               \
                            (int)bcast<unsigned>(v), 16, 64)));               \
            v = __hadd2(v, bcast<__half2>((unsigned)__shfl_xor(               \
                            (int)bcast<unsigned>(v), 32, 64)));
        RED(v0) RED(v1) RED(v2) RED(v3)
        #undef RED
        const float2 lo = __half22float2((g & 1) ? v2 : v0);
        const float2 hi = __half22float2((g & 1) ? v3 : v1);
        if (g < 2) {
            float4 o;
            o.x = lo.x; o.y = lo.y; o.z = hi.x; o.w = hi.y;
            reinterpret_cast<float4*>(outrow + s * U)[t * 2 + g] = o;
        }
    }
}

extern "C" void kernel_launch(void* const* d_in, const int* in_sizes, int n_in,
                              void* d_out, int out_size, void* d_ws, size_t ws_size,
                              hipStream_t stream) {
    const float* x0     = (const float*)d_in[0];
    const float* x1     = (const float*)d_in[1];
    const float* coeffs = (const float*)d_in[2];
    const int*   p0     = (const int*)d_in[3];
    const int*   p1     = (const int*)d_in[4];
    const int*   pout   = (const int*)d_in[5];
    float* out = (float*)d_out;
    WS* ws = (WS*)d_ws;

    build_csr<<<1, 512, 0, stream>>>(coeffs, p0, p1, pout, ws);
    tp_kernel<<<2048, 512, 0, stream>>>(x0, x1, ws, out);
}

// Round 13
// 33.681 us; speedup vs baseline: 1.3062x; 1.0111x over previous
//
#include <hip/hip_runtime.h>
#include <hip/hip_fp16.h>

#define U 128
#define NSEG 32
#define NPATH 512
#define ROW (NSEG * U)     // 4096 elements per batch row
#define NW 8               // waves per tp block (512 threads)
#define NMETA 640          // padded meta capacity (max 512 + 32*3 = 608)
#define RPB 2              // rows per block
#define NBLK 1024          // 2048 / RPB -> exactly 4 blocks/CU, one round

// Path metadata, grouped (order-preserving) by pout, each segment's list
// zero-padded to a multiple of 4. pp = p0 | (p1 << 16); c2 = half2{c, c} bits.
struct Meta { unsigned pp; unsigned c2; };
struct WS {
    Meta meta[NMETA];
    int  segstart[NSEG + 1]; // PADDED CSR boundaries (all multiples of 4)
    int  wsplit[NW + 1];     // segment-boundary split per wave
};

template <typename T, typename F> __device__ inline T bcast(F v) {
    union { F f; T t; } u; u.f = v; return u.t;
}

// One block, 512 threads: thread k owns path k. Deterministic parallel
// counting-sort by pout; per-segment lists zero-padded to x4.
__global__ __launch_bounds__(512) void build_csr(const float* __restrict__ coeffs,
                                                 const int* __restrict__ p0,
                                                 const int* __restrict__ p1,
                                                 const int* __restrict__ pout,
                                                 WS* __restrict__ ws) {
    __shared__ int wcnt[NPATH / 64][NSEG];
    __shared__ int wpre[NPATH / 64][NSEG];
    __shared__ int sseg[NSEG + 1];
    __shared__ int stot[NSEG];

    const int k    = threadIdx.x;
    const int lane = k & 63;
    const int wave = k >> 6;

    const int   po = pout[k];
    const int   a0 = p0[k];
    const int   a1 = p1[k];
    const float c  = coeffs[k];

    // zero ALL meta slots (pads must be {pp=0, c2=0})
    for (int i = k; i < NMETA; i += 512) { Meta z; z.pp = 0u; z.c2 = 0u; ws->meta[i] = z; }

    // rank within wave + per-wave counts, via 32 ballots
    const unsigned long long lt = (1ull << lane) - 1ull;
    int rank = 0;
    #pragma unroll
    for (int s = 0; s < NSEG; ++s) {
        unsigned long long m = __ballot(po == s);
        if (po == s)  rank = (int)__popcll(m & lt);
        if (lane == s) wcnt[wave][s] = (int)__popcll(m);
    }
    __syncthreads();

    // per-segment: prefix over waves + totals (threads 0..31)
    if (k < NSEG) {
        int tot = 0;
        #pragma unroll
        for (int w = 0; w < NPATH / 64; ++w) { wpre[w][k] = tot; tot += wcnt[w][k]; }
        stot[k] = tot;
    }
    __syncthreads();

    // exclusive scan of PADDED totals over segments (wave 0)
    if (k < 64) {
        int v = (k < NSEG) ? ((stot[k] + 3) & ~3) : 0;   // pad to x4
        int inc = v;
        #pragma unroll
        for (int d = 1; d < 64; d <<= 1) {
            int t = __shfl_up(inc, d, 64);
            if (k >= d) inc += t;
        }
        int excl = inc - v;
        if (k < NSEG) sseg[k] = excl;
        if (k == NSEG - 1) sseg[NSEG] = excl + v;
    }
    __syncthreads();

    // scatter (deterministic position within padded segment list)
    {
        const __half   h  = __float2half_rn(c);
        const __half2  h2 = __halves2half2(h, h);
        Meta m;
        m.pp = (unsigned)a0 | ((unsigned)a1 << 16);
        m.c2 = bcast<unsigned>(h2);
        ws->meta[sseg[po] + wpre[wave][po] + rank] = m;
    }
    if (k <= NSEG) ws->segstart[k] = sseg[k];

    // balanced NW-way split boundaries on padded counts (wave 0)
    if (k < 64) {
        const int tot = sseg[NSEG];
        #pragma unroll
        for (int w = 1; w < NW; ++w) {
            const int target = (tot * w) / NW;
            int key;
            if (k <= NSEG) {
                int d = sseg[k] - target; if (d < 0) d = -d;
                key = (d << 6) | k;
            } else key = 0x7fffffff;
            #pragma unroll
            for (int m = 32; m >= 1; m >>= 1) {
                int o = __shfl_xor(key, m, 64);
                key = (o < key) ? o : key;
            }
            if (k == 0) ws->wsplit[w] = key & 63;
        }
        if (k == 0) { ws->wsplit[0] = 0; ws->wsplit[NW] = NSEG; }
    }
}

// One block (512 threads, 8 waves) per TWO batch rows. Both rows in LDS as
// f16, plain layout: row0 x0 [0,ROW), row0 x1 [ROW,2R), row1 x0 [2R,3R),
// row1 x1 [3R,4R) — row1 reads reuse row0 addresses via +2*ROW constant
// (folds into ds_read offset immediate; zero extra address VALU). Quarter
// scheme: lane = 16*g + t; group g takes path j+g; lane reads 8 f16
// (ds_read_b128) at seg*256B + t*16B — conflict-free (each group's 256-B
// span covers all 32 banks evenly). Padded-x4 CSR -> no tails. One meta
// read + 2 addresses feed 16 path-row FMAs.
__global__ __launch_bounds__(512) void tp_kernel(const float* __restrict__ x0,
                                                 const float* __restrict__ x1,
                                                 const WS* __restrict__ ws,
                                                 float* __restrict__ out) {
    __shared__ __align__(16) __half xh[4 * ROW];   // 32 KiB
    __shared__ Meta smeta[NMETA];
    __shared__ int  sseg[NSEG + 1];
    __shared__ int  ssplit[NW + 1];

    const int tid = threadIdx.x;
    const int b0  = blockIdx.x * RPB;

    // stage + convert both rows (coalesced float4 in, uint2 (4xf16) to LDS)
    {
        const float4* g00 = reinterpret_cast<const float4*>(x0 + (size_t)b0 * ROW);
        const float4* g01 = reinterpret_cast<const float4*>(x1 + (size_t)b0 * ROW);
        const float4* g10 = reinterpret_cast<const float4*>(x0 + (size_t)(b0 + 1) * ROW);
        const float4* g11 = reinterpret_cast<const float4*>(x1 + (size_t)(b0 + 1) * ROW);
        #pragma unroll
        for (int j = 0; j < (ROW / 4) / 512; ++j) {   // 2 iters
            const int e = tid + j * 512;              // float4 index
            const float4 v00 = g00[e];
            const float4 v01 = g01[e];
            const float4 v10 = g10[e];
            const float4 v11 = g11[e];
            uint2 h;
            h.x = bcast<unsigned>(__float22half2_rn(make_float2(v00.x, v00.y)));
            h.y = bcast<unsigned>(__float22half2_rn(make_float2(v00.z, v00.w)));
            *reinterpret_cast<uint2*>(&xh[e * 4]) = h;
            h.x = bcast<unsigned>(__float22half2_rn(make_float2(v01.x, v01.y)));
            h.y = bcast<unsigned>(__float22half2_rn(make_float2(v01.z, v01.w)));
            *reinterpret_cast<uint2*>(&xh[ROW + e * 4]) = h;
            h.x = bcast<unsigned>(__float22half2_rn(make_float2(v10.x, v10.y)));
            h.y = bcast<unsigned>(__float22half2_rn(make_float2(v10.z, v10.w)));
            *reinterpret_cast<uint2*>(&xh[2 * ROW + e * 4]) = h;
            h.x = bcast<unsigned>(__float22half2_rn(make_float2(v11.x, v11.y)));
            h.y = bcast<unsigned>(__float22half2_rn(make_float2(v11.z, v11.w)));
            *reinterpret_cast<uint2*>(&xh[3 * ROW + e * 4]) = h;
        }
    }
    if (tid < NMETA / 2)   // 5 KiB of metadata as float4
        reinterpret_cast<float4*>(smeta)[tid] =
            reinterpret_cast<const float4*>(ws->meta)[tid];
    if (tid < NSEG + 1) sseg[tid] = ws->segstart[tid];
    if (tid < NW + 1)   ssplit[tid] = ws->wsplit[tid];
    __syncthreads();

    const int wave = tid >> 6;
    const int lane = tid & 63;
    const int g    = lane >> 4;    // path group 0..3
    const int t    = lane & 15;    // 8-element slot within a segment

    const int sBeg = __builtin_amdgcn_readfirstlane(ssplit[wave]);
    const int sEnd = __builtin_amdgcn_readfirstlane(ssplit[wave + 1]);
    const int tH   = t * 8;        // half-index offset within a segment

    float* outrow0 = out + (size_t)b0 * ROW;
    float* outrow1 = out + (size_t)(b0 + 1) * ROW;

    for (int s = sBeg; s < sEnd; ++s) {
        const int jb = __builtin_amdgcn_readfirstlane(sseg[s]);
        const int je = __builtin_amdgcn_readfirstlane(sseg[s + 1]);
        __half2 a0, a1, a2, a3, b0h, b1h, b2h, b3h;   // row0, row1 accum
        a0 = a1 = a2 = a3 = b0h = b1h = b2h = b3h = bcast<__half2>(0u);
        for (int j = jb; j < je; j += 4) {   // one quad serves 8 path-rows
            const Meta m = smeta[j + g];
            const __half* pu = &xh[(int)(m.pp & 0xffffu) * U + tH];
            const __half* pw = &xh[ROW + (int)(m.pp >> 16) * U + tH];
            const uint4 u0 = *reinterpret_cast<const uint4*>(pu);
            const uint4 w0 = *reinterpret_cast<const uint4*>(pw);
            const uint4 u1 = *reinterpret_cast<const uint4*>(pu + 2 * ROW);
            const uint4 w1 = *reinterpret_cast<const uint4*>(pw + 2 * ROW);
            const __half2 c = bcast<__half2>(m.c2);
            a0  = __hfma2(__hmul2(bcast<__half2>(u0.x), bcast<__half2>(w0.x)), c, a0);
            a1  = __hfma2(__hmul2(bcast<__half2>(u0.y), bcast<__half2>(w0.y)), c, a1);
            a2  = __hfma2(__hmul2(bcast<__half2>(u0.z), bcast<__half2>(w0.z)), c, a2);
            a3  = __hfma2(__hmul2(bcast<__half2>(u0.w), bcast<__half2>(w0.w)), c, a3);
            b0h = __hfma2(__hmul2(bcast<__half2>(u1.x), bcast<__half2>(w1.x)), c, b0h);
            b1h = __hfma2(__hmul2(bcast<__half2>(u1.y), bcast<__half2>(w1.y)), c, b1h);
            b2h = __hfma2(__hmul2(bcast<__half2>(u1.z), bcast<__half2>(w1.z)), c, b2h);
            b3h = __hfma2(__hmul2(bcast<__half2>(u1.w), bcast<__half2>(w1.w)), c, b3h);
        }
        // reduce across the 4 path groups (packed f16), then f32 convert
        #define RED(v)                                                        \
            v = __hadd2(v, bcast<__half2>((unsigned)__shfl_xor(               \
                            (int)bcast<unsigned>(v), 16, 64)));               \
            v = __hadd2(v, bcast<__half2>((unsigned)__shfl_xor(               \
                            (int)bcast<unsigned>(v), 32, 64)));
        RED(a0) RED(a1) RED(a2) RED(a3) RED(b0h) RED(b1h) RED(b2h) RED(b3h)
        #undef RED
        // group g stores: g0/g1 -> row0 halves, g2/g3 -> row1 halves
        const __half2 selLo = (g & 1) ? ((g & 2) ? b2h : a2) : ((g & 2) ? b0h : a0);
        const __half2 selHi = (g & 1) ? ((g & 2) ? b3h : a3) : ((g & 2) ? b1h : a1);
        const float2 lo = __half22float2(selLo);
        const float2 hi = __half22float2(selHi);
        float4 o;
        o.x = lo.x; o.y = lo.y; o.z = hi.x; o.w = hi.y;
        float* orow = (g & 2) ? outrow1 : outrow0;
        reinterpret_cast<float4*>(orow + s * U)[t * 2 + (g & 1)] = o;
    }
}

extern "C" void kernel_launch(void* const* d_in, const int* in_sizes, int n_in,
                              void* d_out, int out_size, void* d_ws, size_t ws_size,
                              hipStream_t stream) {
    const float* x0     = (const float*)d_in[0];
    const float* x1     = (const float*)d_in[1];
    const float* coeffs = (const float*)d_in[2];
    const int*   p0     = (const int*)d_in[3];
    const int*   p1     = (const int*)d_in[4];
    const int*   pout   = (const int*)d_in[5];
    float* out = (float*)d_out;
    WS* ws = (WS*)d_ws;

    build_csr<<<1, 512, 0, stream>>>(coeffs, p0, p1, pout, ws);
    tp_kernel<<<NBLK, 512, 0, stream>>>(x0, x1, ws, out);
}